// Round 8
// baseline (38.237 us; speedup 1.0000x reference)
//
#include <hip/hip_runtime.h>

// Gaussian-splat heatmap as a per-image MFMA GEMM, split into two kernels:
//   A) max_kernel:   one block per image, computes per-image max -> d_ws[b]
//   B) store_kernel: one block per (image, 32-row strip) = 512x7 blocks,
//      recomputes its strip, scales by 1/(max+1e-10), stores. 4 blocks/CU,
//      14-deep pipeline -> stores run at the HBM write roofline while later
//      blocks' build/compute hides underneath.
// Math (identical to r6/r7, bit-identical output):
//   heat[y][x] = sum_p Rmat[y][p] * CmatT[x][p]   (M=N=200 padded to 224, K=64)
//   Rmat[y][p]  = k1n[y-ys_p] if 0<=y-ys_p<ky_p else 0  (top-left-slice quirk)
//   CmatT[x][p] = k1n[x-xs_p] if 0<=x-xs_p<kx_p else 0
// bf16 LDS rows of 128 B, XOR-swizzled byte ^= ((row&7)<<4) (G4/T2).
// mfma_f32_32x32x16_bf16; A-frag: lane l -> row l&31, k=8*(l>>5)+j;
// C/D: col=lane&31, row=(reg&3)+8*(reg>>2)+4*(lane>>5)   [m74/m101]

#define NT 64
#define TDIM 224
#define NTL 7

typedef short bf16x8 __attribute__((ext_vector_type(8)));
typedef float f32x16 __attribute__((ext_vector_type(16)));

// f32 -> bf16 round-to-nearest-even
static __device__ inline unsigned short f2bf(float f) {
    unsigned int u = __float_as_uint(f);
    u = (u + 0x7FFFu + ((u >> 16) & 1u)) >> 16;
    return (unsigned short)u;
}

// per-point-pair metadata from one float4 (points 2q, 2q+1) — replicates reference
struct PMeta { int xs0, ys0, kx0, ky0, xs1, ys1, kx1, ky1; };
static __device__ inline PMeta pmeta(float4 pxy) {
    PMeta m;
    bool v0 = (pxy.x == pxy.x) && (pxy.y == pxy.y);
    int xp0 = (int)(pxy.x * 2.0f), yp0 = 200 - (int)(pxy.y * 2.0f);
    m.xs0 = min(max(xp0 - 18, 0), 164); m.ys0 = min(max(yp0 - 18, 0), 164);
    m.kx0 = v0 ? (min(max(xp0 + 18, 0), 200) - m.xs0) : 0;
    m.ky0 = v0 ? (min(max(yp0 + 18, 0), 200) - m.ys0) : 0;
    bool v1 = (pxy.z == pxy.z) && (pxy.w == pxy.w);
    int xp1 = (int)(pxy.z * 2.0f), yp1 = 200 - (int)(pxy.w * 2.0f);
    m.xs1 = min(max(xp1 - 18, 0), 164); m.ys1 = min(max(yp1 - 18, 0), 164);
    m.kx1 = v1 ? (min(max(xp1 + 18, 0), 200) - m.xs1) : 0;
    m.ky1 = v1 ? (min(max(yp1 + 18, 0), 200) - m.ys1) : 0;
    return m;
}

static __device__ inline void build_k1b(int tid, unsigned short* k1b) {
    if (tid < 37) {
        float sum = 0.0f, mine = 0.0f;
        #pragma unroll
        for (int i = 0; i < 37; ++i) {
            float r = (float)(i - 18);
            float v = expf(-(r * r) * (1.0f / 18.0f));   // sigma=3 -> 2*sigma^2=18
            sum += v;
            if (i == tid) mine = v;
        }
        k1b[tid] = f2bf(mine / sum);
    }
}

// ---------------- kernel A: per-image max ----------------
struct __align__(16) SMemA {
    unsigned short Rm[TDIM][64];   // 28,672 B, swizzled
    unsigned short Cm[TDIM][64];   // 28,672 B, swizzled
    unsigned short k1b[40];
    float wmax[NTL];
};

__global__ __launch_bounds__(448) void max_kernel(const float* __restrict__ x_t,
                                                  float* __restrict__ wsmax) {
    __shared__ SMemA s;
    const int tid  = threadIdx.x;
    const int lane = tid & 63;
    const int wv   = tid >> 6;      // 0..6
    const int b    = blockIdx.x;

    build_k1b(tid, s.k1b);
    __syncthreads();

    {   // build Rm + Cm: thread = (point-pair q, row-group r0)
        const int q  = tid & 31;
        const int r0 = tid >> 5;    // 0..13; rows r0 + 14*i, i=0..15
        PMeta m = pmeta(*(const float4*)(x_t + (size_t)b * NT * 2 + 4 * q));
        #pragma unroll
        for (int i = 0; i < 16; ++i) {
            int row = r0 + 14 * i;
            int sw  = (4 * q) ^ ((row & 7) << 4);
            int d0 = row - m.ys0, d1 = row - m.ys1;
            unsigned a0 = ((unsigned)d0 < (unsigned)m.ky0) ? s.k1b[d0] : 0u;
            unsigned a1 = ((unsigned)d1 < (unsigned)m.ky1) ? s.k1b[d1] : 0u;
            *(unsigned*)((char*)s.Rm + row * 128 + sw) = a0 | (a1 << 16);
            int e0 = row - m.xs0, e1 = row - m.xs1;
            unsigned c0 = ((unsigned)e0 < (unsigned)m.kx0) ? s.k1b[e0] : 0u;
            unsigned c1 = ((unsigned)e1 < (unsigned)m.kx1) ? s.k1b[e1] : 0u;
            *(unsigned*)((char*)s.Cm + row * 128 + sw) = c0 | (c1 << 16);
        }
    }
    __syncthreads();

    const int swl = (lane & 7) << 4;
    bf16x8 A[4];
    {
        const char* ab = (const char*)s.Rm + (wv * 32 + (lane & 31)) * 128;
        #pragma unroll
        for (int m = 0; m < 4; ++m)
            A[m] = *(const bf16x8*)(ab + ((16 * (2 * m + (lane >> 5))) ^ swl));
    }

    float gmax = 0.0f;
    for (int tx = 0; tx < NTL; ++tx) {
        const char* bb = (const char*)s.Cm + (tx * 32 + (lane & 31)) * 128;
        f32x16 acc;
        #pragma unroll
        for (int r = 0; r < 16; ++r) acc[r] = 0.0f;
        #pragma unroll
        for (int m = 0; m < 4; ++m) {
            bf16x8 B = *(const bf16x8*)(bb + ((16 * (2 * m + (lane >> 5))) ^ swl));
            acc = __builtin_amdgcn_mfma_f32_32x32x16_bf16(A[m], B, acc, 0, 0, 0);
        }
        #pragma unroll
        for (int r = 0; r < 16; ++r) gmax = fmaxf(gmax, acc[r]);
    }
    #pragma unroll
    for (int off = 32; off > 0; off >>= 1) gmax = fmaxf(gmax, __shfl_xor(gmax, off));
    if (lane == 0) s.wmax[wv] = gmax;
    __syncthreads();
    if (tid == 0) {
        float mm = s.wmax[0];
        #pragma unroll
        for (int w = 1; w < NTL; ++w) mm = fmaxf(mm, s.wmax[w]);
        wsmax[b] = mm;
    }
}

// ---------------- kernel B: strip recompute + scaled store ----------------
struct __align__(16) SMemB {
    unsigned short Cm[TDIM][64];   // 28,672 B, swizzled (rows = x)
    unsigned short Rm[32][64];     //  4,096 B, swizzled (local rows of this strip)
    unsigned short k1b[40];
};

__global__ __launch_bounds__(256) void store_kernel(const float* __restrict__ x_t,
                                                    const float* __restrict__ wsmax,
                                                    float* __restrict__ out) {
    __shared__ SMemB s;
    const int tid  = threadIdx.x;
    const int lane = tid & 63;
    const int wv   = tid >> 6;      // 0..3
    const int b    = blockIdx.x;
    const int ty   = blockIdx.y;    // 0..6: rows [32*ty, 32*ty+32)

    build_k1b(tid, s.k1b);
    __syncthreads();

    {   // build Cm (all 224 rows) + Rm (this strip's 32 rows)
        const int q  = tid & 31;
        const int r0 = tid >> 5;    // 0..7
        PMeta m = pmeta(*(const float4*)(x_t + (size_t)b * NT * 2 + 4 * q));
        #pragma unroll
        for (int i = 0; i < 28; ++i) {
            int row = r0 + 8 * i;
            int sw  = (4 * q) ^ ((row & 7) << 4);
            int e0 = row - m.xs0, e1 = row - m.xs1;
            unsigned c0 = ((unsigned)e0 < (unsigned)m.kx0) ? s.k1b[e0] : 0u;
            unsigned c1 = ((unsigned)e1 < (unsigned)m.kx1) ? s.k1b[e1] : 0u;
            *(unsigned*)((char*)s.Cm + row * 128 + sw) = c0 | (c1 << 16);
        }
        #pragma unroll
        for (int i = 0; i < 4; ++i) {
            int lr  = r0 + 8 * i;          // local row 0..31
            int row = 32 * ty + lr;        // global y (rows >=200 auto-zero)
            int sw  = (4 * q) ^ ((lr & 7) << 4);
            int d0 = row - m.ys0, d1 = row - m.ys1;
            unsigned a0 = ((unsigned)d0 < (unsigned)m.ky0) ? s.k1b[d0] : 0u;
            unsigned a1 = ((unsigned)d1 < (unsigned)m.ky1) ? s.k1b[d1] : 0u;
            *(unsigned*)((char*)s.Rm + lr * 128 + sw) = a0 | (a1 << 16);
        }
    }
    __syncthreads();

    const float scale = 1.0f / (wsmax[b] + 1e-10f);
    const int swl = (lane & 7) << 4;
    bf16x8 A[4];
    {
        const char* ab = (const char*)s.Rm + (lane & 31) * 128;
        #pragma unroll
        for (int m = 0; m < 4; ++m)
            A[m] = *(const bf16x8*)(ab + ((16 * (2 * m + (lane >> 5))) ^ swl));
    }

    float* ob = out + (size_t)b * (200 * 200);
    #pragma unroll
    for (int t = 0; t < 2; ++t) {
        const int tx = wv + 4 * t;          // waves cover tx = 0..6
        if (tx < NTL) {
            const char* bb = (const char*)s.Cm + (tx * 32 + (lane & 31)) * 128;
            f32x16 acc;
            #pragma unroll
            for (int r = 0; r < 16; ++r) acc[r] = 0.0f;
            #pragma unroll
            for (int m = 0; m < 4; ++m) {
                bf16x8 B = *(const bf16x8*)(bb + ((16 * (2 * m + (lane >> 5))) ^ swl));
                acc = __builtin_amdgcn_mfma_f32_32x32x16_bf16(A[m], B, acc, 0, 0, 0);
            }
            const int gcol = tx * 32 + (lane & 31);
            #pragma unroll
            for (int r = 0; r < 16; ++r) {
                int grow = 32 * ty + (r & 3) + 8 * (r >> 2) + 4 * (lane >> 5);
                if (grow < 200 && gcol < 200)
                    ob[grow * 200 + gcol] = acc[r] * scale;
            }
        }
    }
}

extern "C" void kernel_launch(void* const* d_in, const int* in_sizes, int n_in,
                              void* d_out, int out_size, void* d_ws, size_t ws_size,
                              hipStream_t stream) {
    const float* x_t = (const float*)d_in[0];
    float* out = (float*)d_out;
    float* wsmax = (float*)d_ws;           // 512 floats of scratch
    const int B = in_sizes[0] / (NT * 2);  // 512
    max_kernel<<<B, 448, 0, stream>>>(x_t, wsmax);
    store_kernel<<<dim3(B, NTL), 256, 0, stream>>>(x_t, wsmax, out);
}

// Round 9
// 27.577 us; speedup vs baseline: 1.3865x; 1.3865x over previous
//
#include <hip/hip_runtime.h>

// Gaussian-splat heatmap as a per-image MFMA GEMM — two-pass, optimized build/store.
//   heat[y][x] = sum_p Rmat[y][p] * CmatT[x][p]   (M=N=200 padded to 224, K=64)
//   Rmat[y][p]  = k1n[y-ys_p] if 0<=y-ys_p<ky_p else 0  (top-left-slice quirk)
//   CmatT[x][p] = k1n[x-xs_p] if 0<=x-xs_p<kx_p else 0
// bf16 LDS rows of 128 B, XOR-swizzled byte ^= ((row&7)<<4) (G4/T2).
// Changes vs r6 (24.9 us):
//  * build: 4 points/thread, packed uint2 (b64) LDS writes, k1n via VALU expf
//    (no k1b LDS gathers) -> ~6x less LDS-pipe traffic in the build phase.
//  * operand swap: A=Cm, B=Rm -> D[reg]=x, D[col=lane&31]=y, so each lane's 16
//    accs form 4 contiguous float4 -> 28 dwordx4 stores/lane (was 112 dwords).
//    Same per-element k-summation order -> bit-identical output values.
//  * 448 threads (7 waves, no idle wave). Two-pass (max, then recompute+store),
//    2 blocks/CU (LDS 57.4 KB) -- the R7/R8 post-mortems showed co-residency
//    beats register-held accs (1 blk/CU) and kernel splitting.

#define NT 64
#define TDIM 224
#define NTL 7
#define BLK 448

typedef short bf16x8 __attribute__((ext_vector_type(8)));
typedef float f32x16 __attribute__((ext_vector_type(16)));

// f32 -> bf16 round-to-nearest-even
static __device__ inline unsigned f2bf(float f) {
    unsigned int u = __float_as_uint(f);
    u = (u + 0x7FFFu + ((u >> 16) & 1u)) >> 16;
    return u & 0xFFFFu;
}

struct __align__(16) SMem {
    unsigned short Rm[TDIM][64];   // 28,672 B, swizzled (rows = y)
    unsigned short Cm[TDIM][64];   // 28,672 B, swizzled (rows = x)
    float wmax[NTL];
};

__global__ __launch_bounds__(BLK) void heatmap_kernel(const float* __restrict__ x_t,
                                                      float* __restrict__ out) {
    __shared__ SMem s;
    const int tid  = threadIdx.x;
    const int lane = tid & 63;
    const int wv   = tid >> 6;      // 0..6
    const int b    = blockIdx.x;

    // 1/sum of the 37-tap gaussian (fully unrolled -> constant-folded)
    float ssum = 0.0f;
    #pragma unroll
    for (int i = 0; i < 37; ++i) {
        float r = (float)(i - 18);
        ssum += expf(-(r * r) * (1.0f / 18.0f));   // sigma=3 -> 2*sigma^2=18
    }
    const float invs = 1.0f / ssum;

    // --- build Rm + Cm: thread = (point-quad q4, row-group rg), b64 writes ---
    {
        const int q4 = tid & 15;      // points 4q4..4q4+3
        const int rg = tid >> 4;      // 0..27; rows rg + 28*i, i<8
        const float4 p01 = *(const float4*)(x_t + (size_t)b * 128 + 8 * q4);
        const float4 p23 = *(const float4*)(x_t + (size_t)b * 128 + 8 * q4 + 4);
        float px[4] = {p01.x, p01.z, p23.x, p23.z};
        float py[4] = {p01.y, p01.w, p23.y, p23.w};
        int xs[4], ys[4], kx[4], ky[4];
        #pragma unroll
        for (int k = 0; k < 4; ++k) {   // replicates reference exactly
            bool valid = (px[k] == px[k]) && (py[k] == py[k]);
            int xp = (int)(px[k] * 2.0f);          // trunc == astype(int32), x>=0
            int yp = 200 - (int)(py[k] * 2.0f);
            xs[k] = min(max(xp - 18, 0), 164);
            ys[k] = min(max(yp - 18, 0), 164);
            kx[k] = valid ? (min(max(xp + 18, 0), 200) - xs[k]) : 0;   // <= 36
            ky[k] = valid ? (min(max(yp + 18, 0), 200) - ys[k]) : 0;
        }
        #pragma unroll
        for (int i = 0; i < 8; ++i) {
            const int row = rg + 28 * i;           // covers 0..223
            const int off = (8 * q4) ^ ((row & 7) << 4);
            unsigned rv[4], cv[4];
            #pragma unroll
            for (int k = 0; k < 4; ++k) {
                int d = row - ys[k];
                float fd = (float)(d - 18);
                float v = expf(-(fd * fd) * (1.0f / 18.0f)) * invs;
                rv[k] = ((unsigned)d < (unsigned)ky[k]) ? f2bf(v) : 0u;
                int e = row - xs[k];
                float fe = (float)(e - 18);
                float w = expf(-(fe * fe) * (1.0f / 18.0f)) * invs;
                cv[k] = ((unsigned)e < (unsigned)kx[k]) ? f2bf(w) : 0u;
            }
            uint2 R = {rv[0] | (rv[1] << 16), rv[2] | (rv[3] << 16)};
            *(uint2*)((char*)s.Rm + row * 128 + off) = R;
            uint2 C = {cv[0] | (cv[1] << 16), cv[2] | (cv[3] << 16)};
            *(uint2*)((char*)s.Cm + row * 128 + off) = C;
        }
    }
    __syncthreads();

    const int swl = (lane & 7) << 4;    // swizzle term (rows = t*32+(lane&31))

    // --- B fragments (Rm, this wave's fixed y-tile) ---
    bf16x8 Bf[4];
    {
        const char* rb = (const char*)s.Rm + (wv * 32 + (lane & 31)) * 128;
        #pragma unroll
        for (int m = 0; m < 4; ++m)
            Bf[m] = *(const bf16x8*)(rb + ((16 * (2 * m + (lane >> 5))) ^ swl));
    }

    // --- pass 1: max ---
    float gmax = 0.0f;
    for (int tx = 0; tx < NTL; ++tx) {
        const char* ab = (const char*)s.Cm + (tx * 32 + (lane & 31)) * 128;
        f32x16 acc;
        #pragma unroll
        for (int r = 0; r < 16; ++r) acc[r] = 0.0f;
        #pragma unroll
        for (int m = 0; m < 4; ++m) {
            bf16x8 Af = *(const bf16x8*)(ab + ((16 * (2 * m + (lane >> 5))) ^ swl));
            acc = __builtin_amdgcn_mfma_f32_32x32x16_bf16(Af, Bf[m], acc, 0, 0, 0);
        }
        #pragma unroll
        for (int r = 0; r < 16; ++r) gmax = fmaxf(gmax, acc[r]);
    }
    #pragma unroll
    for (int off = 32; off > 0; off >>= 1) gmax = fmaxf(gmax, __shfl_xor(gmax, off));
    if (lane == 0) s.wmax[wv] = gmax;
    __syncthreads();
    float mm = s.wmax[0];
    #pragma unroll
    for (int w = 1; w < NTL; ++w) mm = fmaxf(mm, s.wmax[w]);
    const float scale = 1.0f / (mm + 1e-10f);

    // --- pass 2: recompute + contiguous float4 stores ---
    // D layout: y = 32*wv + (lane&31)  (col);  x = 32*tx + (r&3)+8*(r>>2)+4*(lane>>5)
    float* ob = out + (size_t)b * (200 * 200);
    const int y  = wv * 32 + (lane & 31);
    const int xh = 4 * (lane >> 5);
    for (int tx = 0; tx < NTL; ++tx) {
        const char* ab = (const char*)s.Cm + (tx * 32 + (lane & 31)) * 128;
        f32x16 acc;
        #pragma unroll
        for (int r = 0; r < 16; ++r) acc[r] = 0.0f;
        #pragma unroll
        for (int m = 0; m < 4; ++m) {
            bf16x8 Af = *(const bf16x8*)(ab + ((16 * (2 * m + (lane >> 5))) ^ swl));
            acc = __builtin_amdgcn_mfma_f32_32x32x16_bf16(Af, Bf[m], acc, 0, 0, 0);
        }
        if (y < 200) {
            #pragma unroll
            for (int g = 0; g < 4; ++g) {
                const int x0 = tx * 32 + 8 * g + xh;
                if (x0 < 200) {   // x0 % 4 == 0, so whole float4 is in-range
                    float4 v = {acc[4 * g] * scale, acc[4 * g + 1] * scale,
                                acc[4 * g + 2] * scale, acc[4 * g + 3] * scale};
                    *(float4*)(ob + (size_t)y * 200 + x0) = v;
                }
            }
        }
    }
}

extern "C" void kernel_launch(void* const* d_in, const int* in_sizes, int n_in,
                              void* d_out, int out_size, void* d_ws, size_t ws_size,
                              hipStream_t stream) {
    const float* x_t = (const float*)d_in[0];
    float* out = (float*)d_out;
    const int B = in_sizes[0] / (NT * 2);   // 512
    heatmap_kernel<<<B, BLK, 0, stream>>>(x_t, out);
}